// Round 8
// baseline (310.793 us; speedup 1.0000x reference)
//
#include <hip/hip_runtime.h>
#include <hip/hip_cooperative_groups.h>
#include <math.h>

namespace cg = cooperative_groups;

#define BATCH 2048
#define LATENT 64
#define LOG_2PI 1.8378770664093453f
#define BETA_M1 5.0f
#define LN2 0.69314718055994530942f
// C2 = -0.5 * log2(e)
#define C2 (-0.72134752044448170368f)

typedef float v2f __attribute__((ext_vector_type(2)));

#define GRID 512
#define DIMB 256   // phase-B dim blocks: l = bx>>2, jc = bx&3 (512 j each)

// ws layout (float units), all f32 (~3.2 MB):
//   Vt   [128][2048]  Vt[2l][j]=C2*inv, Vt[2l+1][j]=C2*m*inv
//   Tce  [64][2048]   Tce[l][j]=C2*(m^2*inv+lv+LOG2PI)
//   Up   [128][2048]  Up[2l][i]=z^2, Up[2l+1][i]=-2z
//   CE   [2048], KLP [2048]
//   LQZ  [2048]       final per-i row logsumexp (log2 domain)
//   PART [16]         [0]=tc atomic, [1]=kl atomic, [2]=done counter
//   PPS  [64][2048]   per-(l,i) exp-sum accumulators (zeroed, atomicAdd)
#define OFF_VT   0
#define OFF_TCE  (128*BATCH)
#define OFF_UP   (OFF_TCE + 64*BATCH)
#define OFF_CE   (OFF_UP + 128*BATCH)
#define OFF_KLP  (OFF_CE + BATCH)
#define OFF_LQZ  (OFF_KLP + BATCH)
#define OFF_PART (OFF_LQZ + BATCH)
#define OFF_PPS  (OFF_PART + 16)

// ---------------- Phase A: precompute (all GRID blocks, 4 j each) ----------------
__device__ __forceinline__ void phaseA(const float* __restrict__ z,
                                       const float* __restrict__ zm,
                                       const float* __restrict__ zlv,
                                       float* __restrict__ ws,
                                       int bx, int t) {
    int jr = t >> 6, l = t & 63;
    int j = bx * 4 + jr;
    int idx = j * LATENT + l;

    float m  = zm[idx];
    float lv = zlv[idx];
    float zv = z[idx];
    float iv  = __expf(-lv);
    float civ = C2 * iv;
    float miv = m * iv;
    float cmv = C2 * miv;
    float cev = C2 * fmaf(m, miv, lv + LOG_2PI);

    ws[OFF_VT  + (2*l)   * BATCH + j] = civ;
    ws[OFF_VT  + (2*l+1) * BATCH + j] = cmv;
    ws[OFF_TCE + l       * BATCH + j] = cev;
    ws[OFF_UP  + (2*l)   * BATCH + j] = zv * zv;
    ws[OFF_UP  + (2*l+1) * BATCH + j] = -2.0f * zv;

    float ce = cev;
    #pragma unroll
    for (int off = 32; off > 0; off >>= 1) ce += __shfl_xor(ce, off, 64);
    if (l == 0) ws[OFF_CE + j] = ce;

    float kp = fmaf(m, m, __expf(lv)) - lv - 1.0f;
    #pragma unroll
    for (int off = 32; off > 0; off >>= 1) kp += __shfl_xor(kp, off, 64);
    if (l == 0) ws[OFF_KLP + j] = kp;

    // zero PPS (1 float/thread: 512*256 = 131072) and PART
    ws[OFF_PPS + bx * 256 + t] = 0.0f;
    if (bx == 0 && t < 16) ws[OFF_PART + t] = 0.0f;
}

// ---------------- Phase B dim: per-(l,i) exp sums over a 512-j chunk ----------------
__device__ __forceinline__ void phaseB_dim(float* __restrict__ ws, int bx2, int t) {
    int l  = bx2 >> 2;
    int jc = bx2 & 3;

    const float* __restrict__ up0 = ws + OFF_UP + (2*l)   * BATCH;
    const float* __restrict__ up1 = ws + OFF_UP + (2*l+1) * BATCH;
    v2f z2p[8], n2p[8], sp[8];
    #pragma unroll
    for (int k = 0; k < 8; ++k) {
        z2p[k] = up0[t + 256*k];   // splat
        n2p[k] = up1[t + 256*k];   // splat
        sp[k]  = 0.0f;
    }

    const v2f* __restrict__ pc2 = (const v2f*)(ws + OFF_VT  + (2*l)   * BATCH + jc * 512);
    const v2f* __restrict__ pm2 = (const v2f*)(ws + OFF_VT  + (2*l+1) * BATCH + jc * 512);
    const v2f* __restrict__ pe2 = (const v2f*)(ws + OFF_TCE + l       * BATCH + jc * 512);

    #pragma unroll 4
    for (int jj = 0; jj < 256; ++jj) {   // 256 pairs = 512 j
        v2f cc = pc2[jj];
        v2f mm = pm2[jj];
        v2f ee = pe2[jj];
        #pragma unroll
        for (int k = 0; k < 8; ++k) {
            v2f e = __builtin_elementwise_fma(z2p[k], cc,
                      __builtin_elementwise_fma(n2p[k], mm, ee));
            v2f x;
            x.x = __builtin_amdgcn_exp2f(e.x);
            x.y = __builtin_amdgcn_exp2f(e.y);
            sp[k] += x;
        }
    }

    float* PPS = ws + OFF_PPS + l * BATCH;
    #pragma unroll
    for (int k = 0; k < 8; ++k)
        atomicAdd(&PPS[t + 256*k], sp[k].x + sp[k].y);
}

// ---------------- Phase B row: 8 i per block, all 2048 j (two 1024-j batches) ----------------
__device__ __forceinline__ void phaseB_row(float* __restrict__ ws, int bx2, int t,
                                           float (*RMs)[4], float (*RSs)[4]) {
    int i0 = bx2 * 8;
    int lane = t & 63, w = t >> 6;

    const float* __restrict__ Vt = ws + OFF_VT;
    const float* __restrict__ Up = ws + OFF_UP;

    float M[8], S[8];
    #pragma unroll
    for (int i = 0; i < 8; ++i) { M[i] = -INFINITY; S[i] = 0.0f; }

    for (int ph = 0; ph < 2; ++ph) {
        int jb = ph * 1024 + 4 * t;
        float r[8][4];
        #pragma unroll
        for (int i = 0; i < 8; ++i)
            r[i][0] = r[i][1] = r[i][2] = r[i][3] = 0.0f;

        for (int l = 0; l < LATENT; ++l) {
            float4 v0 = *(const float4*)(Vt + (2*l)   * BATCH + jb);
            float4 v1 = *(const float4*)(Vt + (2*l+1) * BATCH + jb);
            const float* __restrict__ u0 = Up + (2*l)   * BATCH + i0;  // uniform -> s_load
            const float* __restrict__ u1 = Up + (2*l+1) * BATCH + i0;  // uniform -> s_load
            #pragma unroll
            for (int i = 0; i < 8; ++i) {
                float a = u0[i], b = u1[i];
                r[i][0] = fmaf(a, v0.x, fmaf(b, v1.x, r[i][0]));
                r[i][1] = fmaf(a, v0.y, fmaf(b, v1.y, r[i][1]));
                r[i][2] = fmaf(a, v0.z, fmaf(b, v1.z, r[i][2]));
                r[i][3] = fmaf(a, v0.w, fmaf(b, v1.w, r[i][3]));
            }
        }

        float4 ce4 = *(const float4*)(ws + OFF_CE + jb);
        #pragma unroll
        for (int i = 0; i < 8; ++i) {
            float rc0 = r[i][0] + ce4.x, rc1 = r[i][1] + ce4.y;
            float rc2 = r[i][2] + ce4.z, rc3 = r[i][3] + ce4.w;
            float bM = fmaxf(fmaxf(rc0, rc1), fmaxf(rc2, rc3));
            float bS = __builtin_amdgcn_exp2f(rc0 - bM) + __builtin_amdgcn_exp2f(rc1 - bM)
                     + __builtin_amdgcn_exp2f(rc2 - bM) + __builtin_amdgcn_exp2f(rc3 - bM);
            float mn = fmaxf(M[i], bM);
            S[i] = S[i] * __builtin_amdgcn_exp2f(M[i] - mn)
                 + bS  * __builtin_amdgcn_exp2f(bM  - mn);
            M[i] = mn;
        }
    }

    #pragma unroll
    for (int i = 0; i < 8; ++i) {
        float Mi = M[i], Si = S[i];
        #pragma unroll
        for (int off = 32; off > 0; off >>= 1) {
            float Mo = __shfl_xor(Mi, off, 64);
            float So = __shfl_xor(Si, off, 64);
            float mn = fmaxf(Mi, Mo);
            Si = Si * __builtin_amdgcn_exp2f(Mi - mn) + So * __builtin_amdgcn_exp2f(Mo - mn);
            Mi = mn;
        }
        if (lane == 0) { RMs[i][w] = Mi; RSs[i][w] = Si; }
    }
    __syncthreads();
    if (t < 8) {
        float Mi = RMs[t][0], Si = RSs[t][0];
        #pragma unroll
        for (int w2 = 1; w2 < 4; ++w2) {
            float Mo = RMs[t][w2], So = RSs[t][w2];
            float mn = fmaxf(Mi, Mo);
            Si = Si * __builtin_amdgcn_exp2f(Mi - mn) + So * __builtin_amdgcn_exp2f(Mo - mn);
            Mi = mn;
        }
        ws[OFF_LQZ + i0 + t] = Mi + __builtin_amdgcn_logf(Si);
    }
}

// ---------------- Phase C: flat finalize, last-done block writes out ----------------
__device__ __forceinline__ void phaseC(float* __restrict__ ws, float* __restrict__ out,
                                       int bx, int t, float* s_tc, float* s_kl) {
    int gid = bx * 256 + t;                       // 0..131071 == l*2048+i
    float acc = -__builtin_amdgcn_logf(ws[OFF_PPS + gid]);
    float kl = 0.0f;
    if (gid < BATCH) {
        acc += ws[OFF_LQZ + gid];
        kl = ws[OFF_KLP + gid];
    }
    s_tc[t] = acc; s_kl[t] = kl;
    __syncthreads();
    for (int s = 128; s > 0; s >>= 1) {
        if (t < s) { s_tc[t] += s_tc[t + s]; s_kl[t] += s_kl[t + s]; }
        __syncthreads();
    }
    if (t == 0) {
        atomicAdd(&ws[OFF_PART + 0], s_tc[0]);
        atomicAdd(&ws[OFF_PART + 1], s_kl[0]);
        __threadfence();
        unsigned prev = atomicAdd((unsigned*)(ws + OFF_PART + 2), 1u);
        if (prev == (unsigned)(GRID - 1)) {
            __threadfence();
            float tc  = ws[OFF_PART + 0];
            float kl2 = ws[OFF_PART + 1];
            out[0] = BETA_M1 * (LN2 * tc / (float)BATCH) + 0.5f * (kl2 / (float)BATCH);
        }
    }
}

// ---------------- Cooperative fused kernel ----------------
__global__ __launch_bounds__(256, 4) void fused_kernel(const float* __restrict__ z,
                                                       const float* __restrict__ zm,
                                                       const float* __restrict__ zlv,
                                                       float* __restrict__ ws,
                                                       float* __restrict__ out) {
    __shared__ float RMs[8][4], RSs[8][4];
    __shared__ float s_tc[256], s_kl[256];
    cg::grid_group grid = cg::this_grid();
    int bx = blockIdx.x, t = threadIdx.x;

    phaseA(z, zm, zlv, ws, bx, t);
    grid.sync();
    if (bx < DIMB) phaseB_dim(ws, bx, t);
    else           phaseB_row(ws, bx - DIMB, t, RMs, RSs);
    grid.sync();
    phaseC(ws, out, bx, t, s_tc, s_kl);
}

// ---------------- Fallback plain kernels (same phases, 3 launches) ----------------
__global__ __launch_bounds__(256) void k_pre(const float* __restrict__ z,
                                             const float* __restrict__ zm,
                                             const float* __restrict__ zlv,
                                             float* __restrict__ ws) {
    phaseA(z, zm, zlv, ws, blockIdx.x, threadIdx.x);
}

__global__ __launch_bounds__(256) void k_main(float* __restrict__ ws) {
    __shared__ float RMs[8][4], RSs[8][4];
    int bx = blockIdx.x, t = threadIdx.x;
    if (bx < DIMB) phaseB_dim(ws, bx, t);
    else           phaseB_row(ws, bx - DIMB, t, RMs, RSs);
}

__global__ __launch_bounds__(256) void k_fin(float* __restrict__ ws,
                                             float* __restrict__ out) {
    __shared__ float s_tc[256], s_kl[256];
    phaseC(ws, out, blockIdx.x, threadIdx.x, s_tc, s_kl);
}

extern "C" void kernel_launch(void* const* d_in, const int* in_sizes, int n_in,
                              void* d_out, int out_size, void* d_ws, size_t ws_size,
                              hipStream_t stream) {
    const float* z        = (const float*)d_in[0];
    const float* z_mean   = (const float*)d_in[1];
    const float* z_logvar = (const float*)d_in[2];
    float* out = (float*)d_out;
    float* ws  = (float*)d_ws;

    void* args[] = { (void*)&z, (void*)&z_mean, (void*)&z_logvar,
                     (void*)&ws, (void*)&out };
    hipError_t e = hipLaunchCooperativeKernel((void*)fused_kernel, dim3(GRID),
                                              dim3(256), args, 0, stream);
    if (e != hipSuccess) {
        (void)hipGetLastError();   // clear sticky error, take the plain path
        k_pre<<<GRID, 256, 0, stream>>>(z, z_mean, z_logvar, ws);
        k_main<<<GRID, 256, 0, stream>>>(ws);
        k_fin<<<GRID, 256, 0, stream>>>(ws, out);
    }
}

// Round 9
// 154.512 us; speedup vs baseline: 2.0114x; 2.0114x over previous
//
#include <hip/hip_runtime.h>
#include <math.h>

#define BATCH 2048
#define LATENT 64
#define LOG_2PI 1.8378770664093453f
#define BETA_M1 5.0f
#define LN2 0.69314718055994530942f
// C2 = -0.5 * log2(e)
#define C2 (-0.72134752044448170368f)

// ws layout (float units), all f32 (~3.2 MB):
//   Vt   [128][2048]  Vt[2l][j]=C2*inv, Vt[2l+1][j]=C2*m*inv
//   Tce  [64][2048]   Tce[l][j]=C2*(m^2*inv+lv+LOG2PI)
//   Up   [128][2048]  Up[2l][i]=z^2, Up[2l+1][i]=-2z
//   CE   [2048], KLP [2048]
//   RMP/RSP [2][2048] row-LSE partials (log2 domain)
//   PART [16]         [0]=tc atomic, [1]=kl atomic, [2]=done counter
//   PPS  [64][2048]   per-(l,i) exp-sum accumulators (zeroed, atomicAdd)
#define OFF_VT   0
#define OFF_TCE  (128*BATCH)
#define OFF_UP   (OFF_TCE + 64*BATCH)
#define OFF_CE   (OFF_UP + 128*BATCH)
#define OFF_KLP  (OFF_CE + BATCH)
#define OFF_RMP  (OFF_KLP + BATCH)
#define OFF_RSP  (OFF_RMP + 2*BATCH)
#define OFF_PART (OFF_RSP + 2*BATCH)
#define OFF_PPS  (OFF_PART + 16)

// Precompute: 512 blocks x 256 thr, 4 j per block. Coalesced reads
// (t&63 = l), scattered small writes. Also zeroes PPS and PART.
__global__ __launch_bounds__(256) void pre_kernel(const float* __restrict__ z,
                                                  const float* __restrict__ zm,
                                                  const float* __restrict__ zlv,
                                                  float* __restrict__ ws) {
    int bx = blockIdx.x, t = threadIdx.x;
    int jr = t >> 6, l = t & 63;
    int j = bx * 4 + jr;
    int idx = j * LATENT + l;

    float m  = zm[idx];
    float lv = zlv[idx];
    float zv = z[idx];
    float iv  = __expf(-lv);
    float civ = C2 * iv;
    float miv = m * iv;
    float cmv = C2 * miv;
    float cev = C2 * fmaf(m, miv, lv + LOG_2PI);

    ws[OFF_VT  + (2*l)   * BATCH + j] = civ;
    ws[OFF_VT  + (2*l+1) * BATCH + j] = cmv;
    ws[OFF_TCE + l       * BATCH + j] = cev;
    ws[OFF_UP  + (2*l)   * BATCH + j] = zv * zv;
    ws[OFF_UP  + (2*l+1) * BATCH + j] = -2.0f * zv;

    float ce = cev;
    #pragma unroll
    for (int off = 32; off > 0; off >>= 1) ce += __shfl_xor(ce, off, 64);
    if (l == 0) ws[OFF_CE + j] = ce;

    float kp = fmaf(m, m, __expf(lv)) - lv - 1.0f;
    #pragma unroll
    for (int off = 32; off > 0; off >>= 1) kp += __shfl_xor(kp, off, 64);
    if (l == 0) ws[OFF_KLP + j] = kp;

    ws[OFF_PPS + bx * 256 + t] = 0.0f;          // 512*256 = 131072 floats
    if (bx == 0 && t < 16) ws[OFF_PART + t] = 0.0f;
}

// Fused main, 1024 blocks interleaved: even bx -> dim path, odd bx -> row path.
// dim: l = b>>3, jc = b&7 (256-j chunk), 8 i/thread (all 2048 i).
// row: 8 i per block-pair index, one 1024-j half each.
__global__ __launch_bounds__(256) void main_kernel(float* __restrict__ ws) {
    __shared__ float RMs[8][4], RSs[8][4];
    int bx = blockIdx.x, t = threadIdx.x;
    int b = bx >> 1;

    if ((bx & 1) == 0) {
        // ---- dim path ----
        int l  = b >> 3;
        int jc = b & 7;

        const float* __restrict__ up0 = ws + OFF_UP + (2*l)   * BATCH;
        const float* __restrict__ up1 = ws + OFF_UP + (2*l+1) * BATCH;
        float z2[8], n2[8], s[8];
        #pragma unroll
        for (int k = 0; k < 8; ++k) {
            z2[k] = up0[t + 256*k];
            n2[k] = up1[t + 256*k];
            s[k]  = 0.0f;
        }

        const float* __restrict__ pc = ws + OFF_VT  + (2*l)   * BATCH + jc * 256;
        const float* __restrict__ pm = ws + OFF_VT  + (2*l+1) * BATCH + jc * 256;
        const float* __restrict__ pe = ws + OFF_TCE + l       * BATCH + jc * 256;

        for (int jj = 0; jj < 256; jj += 8) {
            #pragma unroll
            for (int u = 0; u < 8; ++u) {
                float cc = pc[jj + u];
                float mm = pm[jj + u];
                float ee = pe[jj + u];
                #pragma unroll
                for (int k = 0; k < 8; ++k)
                    s[k] += __builtin_amdgcn_exp2f(fmaf(z2[k], cc, fmaf(n2[k], mm, ee)));
            }
        }

        float* PPS = ws + OFF_PPS + l * BATCH;
        #pragma unroll
        for (int k = 0; k < 8; ++k)
            atomicAdd(&PPS[t + 256*k], s[k]);
    } else {
        // ---- row path ----
        int ib8 = b >> 1, ph = b & 1;
        int i0 = ib8 * 8;
        int jb = ph * 1024 + 4 * t;
        int lane = t & 63, w = t >> 6;

        const float* __restrict__ Vt = ws + OFF_VT;
        const float* __restrict__ Up = ws + OFF_UP;

        float r[8][4];
        #pragma unroll
        for (int i = 0; i < 8; ++i)
            r[i][0] = r[i][1] = r[i][2] = r[i][3] = 0.0f;

        for (int l = 0; l < LATENT; ++l) {
            float4 v0 = *(const float4*)(Vt + (2*l)   * BATCH + jb);
            float4 v1 = *(const float4*)(Vt + (2*l+1) * BATCH + jb);
            const float* __restrict__ u0 = Up + (2*l)   * BATCH + i0;  // uniform -> s_load
            const float* __restrict__ u1 = Up + (2*l+1) * BATCH + i0;  // uniform -> s_load
            #pragma unroll
            for (int i = 0; i < 8; ++i) {
                float a = u0[i], bb = u1[i];
                r[i][0] = fmaf(a, v0.x, fmaf(bb, v1.x, r[i][0]));
                r[i][1] = fmaf(a, v0.y, fmaf(bb, v1.y, r[i][1]));
                r[i][2] = fmaf(a, v0.z, fmaf(bb, v1.z, r[i][2]));
                r[i][3] = fmaf(a, v0.w, fmaf(bb, v1.w, r[i][3]));
            }
        }

        float4 ce4 = *(const float4*)(ws + OFF_CE + jb);
        #pragma unroll
        for (int i = 0; i < 8; ++i) {
            float rc0 = r[i][0] + ce4.x, rc1 = r[i][1] + ce4.y;
            float rc2 = r[i][2] + ce4.z, rc3 = r[i][3] + ce4.w;
            float M = fmaxf(fmaxf(rc0, rc1), fmaxf(rc2, rc3));
            float S = __builtin_amdgcn_exp2f(rc0 - M) + __builtin_amdgcn_exp2f(rc1 - M)
                    + __builtin_amdgcn_exp2f(rc2 - M) + __builtin_amdgcn_exp2f(rc3 - M);
            #pragma unroll
            for (int off = 32; off > 0; off >>= 1) {
                float Mo = __shfl_xor(M, off, 64);
                float So = __shfl_xor(S, off, 64);
                float mn = fmaxf(M, Mo);
                S = S * __builtin_amdgcn_exp2f(M - mn) + So * __builtin_amdgcn_exp2f(Mo - mn);
                M = mn;
            }
            if (lane == 0) { RMs[i][w] = M; RSs[i][w] = S; }
        }
        __syncthreads();
        if (t < 8) {
            float M = RMs[t][0], S = RSs[t][0];
            #pragma unroll
            for (int w2 = 1; w2 < 4; ++w2) {
                float Mo = RMs[t][w2], So = RSs[t][w2];
                float mn = fmaxf(M, Mo);
                S = S * __builtin_amdgcn_exp2f(M - mn) + So * __builtin_amdgcn_exp2f(Mo - mn);
                M = mn;
            }
            ws[OFF_RMP + ph * BATCH + i0 + t] = M;
            ws[OFF_RSP + ph * BATCH + i0 + t] = S;
        }
    }
}

// Finalize: 512 blocks x 256, one PPS element per thread; first 2048 threads
// also merge row-LSE halves + KL. Last-done block assembles out[0].
__global__ __launch_bounds__(256) void fin_kernel(float* __restrict__ ws,
                                                  float* __restrict__ out) {
    __shared__ float s_tc[256], s_kl[256];
    int bx = blockIdx.x, t = threadIdx.x;
    int gid = bx * 256 + t;                       // 0..131071 == l*2048+i

    float acc = -__builtin_amdgcn_logf(ws[OFF_PPS + gid]);
    float kl = 0.0f;
    if (gid < BATCH) {
        int i = gid;
        float M0 = ws[OFF_RMP + i], M1 = ws[OFF_RMP + BATCH + i];
        float S0 = ws[OFF_RSP + i], S1 = ws[OFF_RSP + BATCH + i];
        float mn = fmaxf(M0, M1);
        acc += mn + __builtin_amdgcn_logf(
            S0 * __builtin_amdgcn_exp2f(M0 - mn) + S1 * __builtin_amdgcn_exp2f(M1 - mn));
        kl = ws[OFF_KLP + i];
    }

    s_tc[t] = acc; s_kl[t] = kl;
    __syncthreads();
    for (int s = 128; s > 0; s >>= 1) {
        if (t < s) { s_tc[t] += s_tc[t + s]; s_kl[t] += s_kl[t + s]; }
        __syncthreads();
    }
    if (t == 0) {
        atomicAdd(&ws[OFF_PART + 0], s_tc[0]);
        atomicAdd(&ws[OFF_PART + 1], s_kl[0]);
        __threadfence();
        unsigned prev = atomicAdd((unsigned*)(ws + OFF_PART + 2), 1u);
        if (prev == 511u) {
            __threadfence();
            float tc  = ws[OFF_PART + 0];
            float kl2 = ws[OFF_PART + 1];
            out[0] = BETA_M1 * (LN2 * tc / (float)BATCH) + 0.5f * (kl2 / (float)BATCH);
        }
    }
}

extern "C" void kernel_launch(void* const* d_in, const int* in_sizes, int n_in,
                              void* d_out, int out_size, void* d_ws, size_t ws_size,
                              hipStream_t stream) {
    const float* z        = (const float*)d_in[0];
    const float* z_mean   = (const float*)d_in[1];
    const float* z_logvar = (const float*)d_in[2];
    float* out = (float*)d_out;
    float* ws  = (float*)d_ws;

    pre_kernel<<<512, 256, 0, stream>>>(z, z_mean, z_logvar, ws);
    main_kernel<<<1024, 256, 0, stream>>>(ws);
    fin_kernel<<<512, 256, 0, stream>>>(ws, out);
}